// Round 7
// baseline (454.164 us; speedup 1.0000x reference)
//
#include <hip/hip_runtime.h>
#include <hip/hip_bf16.h>

typedef unsigned short u16;

#define B_   16
#define OC   256
#define ZD   64
#define NG_  8
#define EPS  1e-5f

typedef __attribute__((ext_vector_type(8))) __bf16 bf16x8;
typedef __attribute__((ext_vector_type(4))) float f32x4;
typedef __attribute__((ext_vector_type(8))) u16 ushort8;
typedef __attribute__((ext_vector_type(4))) u16 u16x4;

// Workspace layout (bytes), total ~71.3 MB (byte-identical to round-2 map)
#define OFF_XT  ((size_t)0)          // xT  bf16 [16][4096][128] = 16,777,216
#define OFF_A1  ((size_t)16777216)   // A1  bf16 [16][256][1152] =  9,437,184
#define OFF_A2  ((size_t)26214400)   // A2  bf16 [16][256][2304] = 18,874,368
#define OFF_ASC ((size_t)45088768)   // Asc bf16 [16][256][128]  =  1,048,576
#define OFF_O12 ((size_t)46137344)   // out1/out2 fp32 [16][1024][256] = 16,777,216
#define OFF_YT  ((size_t)62914560)   // yT  bf16 [16][1024][256] =  8,388,608
#define OFF_ST1 ((size_t)71303168)   // raw sums (s,s2) per (b,g): 1 KB
#define OFF_ST2 ((size_t)71304192)   // 1 KB
#define OFF_ZP  ((size_t)71305216)   // 512 B zero page

__device__ __forceinline__ u16 f2bf(float f) {
    union { float f; unsigned u; } x; x.f = f;
    unsigned r = x.u + 0x7fffu + ((x.u >> 16) & 1u);   // RNE
    return (u16)(r >> 16);
}

#define GLD16(gp, lp) __builtin_amdgcn_global_load_lds(                    \
        (const __attribute__((address_space(1))) void*)(gp),               \
        (__attribute__((address_space(3))) void*)(lp), 16, 0, 0)

// ---------------------------------------------------------------------------
// x NCHW fp32 -> xT [b][n=4096][ic=128] bf16.
// ---------------------------------------------------------------------------
__global__ void transpose_x_kern(const float* __restrict__ x, u16* __restrict__ xT) {
    const int b = blockIdx.z, ic0 = blockIdx.y * 32;
    const int n = blockIdx.x * 256 + threadIdx.x;
    const float* xp = x + ((size_t)b * 128 + ic0) * 4096 + n;
    u16* op = xT + ((size_t)b * 4096 + n) * 128 + ic0;
    float v[32];
    #pragma unroll
    for (int i = 0; i < 32; ++i) v[i] = xp[(size_t)i * 4096];
    #pragma unroll
    for (int c = 0; c < 4; ++c) {
        ushort8 o;
        #pragma unroll
        for (int j = 0; j < 8; ++j) o[j] = f2bf(v[c * 8 + j]);
        *(ushort8*)(op + c * 8) = o;
    }
}

// ---------------------------------------------------------------------------
// Weight gen as MFMA GEMM, output-coalesced, double-tile (round-6 verified,
// unchanged).
// ---------------------------------------------------------------------------
template<int ICk, int KD>
__device__ __forceinline__ void gen_w_tile2(const float* __restrict__ hw,
                                            const float* __restrict__ hb,
                                            const float* __restrict__ bw,
                                            const float* __restrict__ z,
                                            u16* __restrict__ A, int t2) {
    const int lane = threadIdx.x & 63;
    const int l16 = lane & 15, q = lane >> 4;
    const int q8 = q * 8, q4 = q * 4;
    constexpr int ICT2 = ICk / 32;         // 32-ic double-tiles per (oc, d)
    constexpr int K = ICk * KD;

    const int oc  = t2 / (KD * ICT2);
    const int rem = t2 - oc * (KD * ICT2);
    const int d   = rem / ICT2;
    const int ic0 = (rem - d * ICT2) * 32;

    // hw rows for both sub-tiles: issue all 8 float4 loads up front
    const size_t nrow0 = (size_t)(oc * ICk + ic0 + l16) * KD + d;
    const float* hp0 = hw + nrow0 * ZD + q8;
    const float* hp1 = hp0 + (size_t)16 * KD * ZD;
    float4 a0 = *(const float4*)hp0,        a1 = *(const float4*)(hp0 + 4);
    float4 a2 = *(const float4*)(hp0 + 32), a3 = *(const float4*)(hp0 + 36);
    float4 c0 = *(const float4*)hp1,        c1 = *(const float4*)(hp1 + 4);
    float4 c2 = *(const float4*)(hp1 + 32), c3 = *(const float4*)(hp1 + 36);

    // z b-frags: z[batch=l16][k=q8+j] fp32 -> bf16 in-register
    const float* zpp = z + l16 * ZD + q8;
    float4 z0 = *(const float4*)zpp,        z1 = *(const float4*)(zpp + 4);
    float4 z2 = *(const float4*)(zpp + 32), z3 = *(const float4*)(zpp + 36);
    union { ushort8 u; bf16x8 h; } zb0, zb1;
    zb0.u[0]=f2bf(z0.x); zb0.u[1]=f2bf(z0.y); zb0.u[2]=f2bf(z0.z); zb0.u[3]=f2bf(z0.w);
    zb0.u[4]=f2bf(z1.x); zb0.u[5]=f2bf(z1.y); zb0.u[6]=f2bf(z1.z); zb0.u[7]=f2bf(z1.w);
    zb1.u[0]=f2bf(z2.x); zb1.u[1]=f2bf(z2.y); zb1.u[2]=f2bf(z2.z); zb1.u[3]=f2bf(z2.w);
    zb1.u[4]=f2bf(z3.x); zb1.u[5]=f2bf(z3.y); zb1.u[6]=f2bf(z3.z); zb1.u[7]=f2bf(z3.w);

    union { ushort8 u; bf16x8 h; } wa0, wa1, wc0, wc1;
    wa0.u[0]=f2bf(a0.x); wa0.u[1]=f2bf(a0.y); wa0.u[2]=f2bf(a0.z); wa0.u[3]=f2bf(a0.w);
    wa0.u[4]=f2bf(a1.x); wa0.u[5]=f2bf(a1.y); wa0.u[6]=f2bf(a1.z); wa0.u[7]=f2bf(a1.w);
    wa1.u[0]=f2bf(a2.x); wa1.u[1]=f2bf(a2.y); wa1.u[2]=f2bf(a2.z); wa1.u[3]=f2bf(a2.w);
    wa1.u[4]=f2bf(a3.x); wa1.u[5]=f2bf(a3.y); wa1.u[6]=f2bf(a3.z); wa1.u[7]=f2bf(a3.w);
    wc0.u[0]=f2bf(c0.x); wc0.u[1]=f2bf(c0.y); wc0.u[2]=f2bf(c0.z); wc0.u[3]=f2bf(c0.w);
    wc0.u[4]=f2bf(c1.x); wc0.u[5]=f2bf(c1.y); wc0.u[6]=f2bf(c1.z); wc0.u[7]=f2bf(c1.w);
    wc1.u[0]=f2bf(c2.x); wc1.u[1]=f2bf(c2.y); wc1.u[2]=f2bf(c2.z); wc1.u[3]=f2bf(c2.w);
    wc1.u[4]=f2bf(c3.x); wc1.u[5]=f2bf(c3.y); wc1.u[6]=f2bf(c3.z); wc1.u[7]=f2bf(c3.w);

    f32x4 accA = {0.f, 0.f, 0.f, 0.f}, accC = {0.f, 0.f, 0.f, 0.f};
    accA = __builtin_amdgcn_mfma_f32_16x16x32_bf16(wa0.h, zb0.h, accA, 0, 0, 0);
    accA = __builtin_amdgcn_mfma_f32_16x16x32_bf16(wa1.h, zb1.h, accA, 0, 0, 0);
    accC = __builtin_amdgcn_mfma_f32_16x16x32_bf16(wc0.h, zb0.h, accC, 0, 0, 0);
    accC = __builtin_amdgcn_mfma_f32_16x16x32_bf16(wc1.h, zb1.h, accC, 0, 0, 0);

    // base + bias for lane's 4 rows of each sub-tile (stride-KD gather)
    const size_t nb0 = (size_t)(oc * ICk + ic0 + q4) * KD + d;
    const size_t nb1 = nb0 + (size_t)16 * KD;
    float bsA[4], bsC[4];
    #pragma unroll
    for (int r = 0; r < 4; ++r) {
        bsA[r] = bw[nb0 + (size_t)r * KD] + hb[nb0 + (size_t)r * KD];
        bsC[r] = bw[nb1 + (size_t)r * KD] + hb[nb1 + (size_t)r * KD];
    }

    // D layout: col(l16)=batch, row(q*4+r)=ic offset -> 4 consecutive ic.
    u16* op = A + ((size_t)l16 * OC + oc) * (size_t)K + (size_t)d * ICk + ic0 + q4;
    u16x4 oA, oC;
    #pragma unroll
    for (int r = 0; r < 4; ++r) { oA[r] = f2bf(accA[r] + bsA[r]); oC[r] = f2bf(accC[r] + bsC[r]); }
    *(u16x4*)op = oA;
    *(u16x4*)(op + 16) = oC;
}

__global__ __launch_bounds__(256)
void gen_all_kern(const float* __restrict__ hw1, const float* __restrict__ hb1,
                  const float* __restrict__ bw1,
                  const float* __restrict__ hw2, const float* __restrict__ hb2,
                  const float* __restrict__ bw2,
                  const float* __restrict__ hwsc, const float* __restrict__ hbsc,
                  const float* __restrict__ bwsc,
                  const float* __restrict__ z,
                  u16* __restrict__ A1, u16* __restrict__ A2, u16* __restrict__ Asc) {
    const int wid = threadIdx.x >> 6;
    const int bx = blockIdx.x;
    if (bx < 4608) {
        gen_w_tile2<256, 9>(hw2, hb2, bw2, z, A2, bx * 4 + wid);            // 18432 t2
    } else if (bx < 6912) {
        gen_w_tile2<128, 9>(hw1, hb1, bw1, z, A1, (bx - 4608) * 4 + wid);   // 9216 t2
    } else {
        gen_w_tile2<128, 1>(hwsc, hbsc, bwsc, z, Asc, (bx - 6912) * 4 + wid); // 1024
    }
}

// ---------------------------------------------------------------------------
// GN1 apply + ReLU + bf16: out1 [b][n][256] fp32 -> yT bf16.
// stats holds RAW (s, s2) sums per (b,g); finalize inline.
// ---------------------------------------------------------------------------
__global__ void gn_apply_kern(const float* __restrict__ o1, const float* __restrict__ stats,
                              const float* __restrict__ gamma, const float* __restrict__ beta,
                              u16* __restrict__ yT) {
    const int gtid = blockIdx.x * 256 + threadIdx.x;
    const int c8 = gtid & 31;
    const int n  = (gtid >> 5) & 1023;
    const int b  = gtid >> 15;
    const int g  = c8 >> 2;
    const float s  = stats[(b * NG_ + g) * 2 + 0];
    const float s2 = stats[(b * NG_ + g) * 2 + 1];
    const float mean = s * (1.0f / 32768.0f);
    const float rstd = rsqrtf(s2 * (1.0f / 32768.0f) - mean * mean + EPS);
    const float* src = o1 + ((size_t)b * 1024 + n) * 256 + c8 * 8;
    float4 v0 = *(const float4*)src, v1 = *(const float4*)(src + 4);
    float4 g0 = *(const float4*)(gamma + c8 * 8), g1 = *(const float4*)(gamma + c8 * 8 + 4);
    float4 b0 = *(const float4*)(beta  + c8 * 8), b1 = *(const float4*)(beta  + c8 * 8 + 4);
    ushort8 o;
    o[0] = f2bf(fmaxf((v0.x - mean) * rstd * g0.x + b0.x, 0.f));
    o[1] = f2bf(fmaxf((v0.y - mean) * rstd * g0.y + b0.y, 0.f));
    o[2] = f2bf(fmaxf((v0.z - mean) * rstd * g0.z + b0.z, 0.f));
    o[3] = f2bf(fmaxf((v0.w - mean) * rstd * g0.w + b0.w, 0.f));
    o[4] = f2bf(fmaxf((v1.x - mean) * rstd * g1.x + b1.x, 0.f));
    o[5] = f2bf(fmaxf((v1.y - mean) * rstd * g1.y + b1.y, 0.f));
    o[6] = f2bf(fmaxf((v1.z - mean) * rstd * g1.z + b1.z, 0.f));
    o[7] = f2bf(fmaxf((v1.w - mean) * rstd * g1.w + b1.w, 0.f));
    *(ushort8*)(yT + ((size_t)b * 1024 + n) * 256 + c8 * 8) = o;
}

// ---------------------------------------------------------------------------
// Implicit-im2col MFMA conv GEMM, 64x128 tile, 2-PHASE DOUBLE-BUFFERED:
// per K-step, issue next step's 3 global_load_lds BEFORE computing current
// step, ONE barrier per step (was 2 + full vmcnt drain on critical path).
// Steps flattened: s -> (d = s/ICN, ic0 = (s%ICN)*32), ICN power of 2.
// EPI=0: plain stores + fused GN partial stats. EPI=1: GN2-apply+add+ReLU.
// ---------------------------------------------------------------------------
template<int IC, int IH, int STRIDE, int KD, int EPI>
__global__ __launch_bounds__(256, 2)
void conv_gemm(const u16* __restrict__ F, const u16* __restrict__ Wm,
               float* __restrict__ C, const u16* __restrict__ zp,
               const float* __restrict__ D2, float* __restrict__ stats,
               const float* __restrict__ gamma, const float* __restrict__ beta) {
    constexpr int K   = IC * KD;
    constexpr int PAD = (KD == 9) ? 1 : 0;
    constexpr int ICN = IC / 32;         // 4 or 8 (power of 2)
    constexpr int NT  = KD * ICN;        // 36 / 72 / 4 K-steps
    __shared__ __align__(16) u16 As[2][64 * 32];
    __shared__ __align__(16) u16 Bs[2][128 * 32];

    const int b  = blockIdx.z;
    const int m0 = blockIdx.y * 64;      // spatial
    const int n0 = blockIdx.x * 128;     // oc
    const int tid = threadIdx.x, lane = tid & 63, wid = tid >> 6;
    const int wm = (wid >> 1) * 32, wn = (wid & 1) * 64;
    const int lr  = lane >> 2;
    const int lc  = (lane & 3) * 8;      // u16 offset within 64B row segment
    const int l16 = lane & 15, q8 = (lane >> 4) * 8;

    // spatial coords of this lane's A-staging row
    const int ra0 = m0 + wid * 16 + lr;
    const int y0 = ra0 >> 5, x0 = ra0 & 31;
    const size_t fb = (size_t)b * IH * IH * IC;

    const u16* q0 = Wm + ((size_t)b * OC + n0 + wid * 16 + lr) * K + lc;
    const u16* q1 = q0 + (size_t)64 * K;

    // issue the 3 staging loads for step s into buffer `bi`
    auto stage = [&](int bi, int s) {
        const int d   = s / ICN;
        const int ic0 = (s - d * ICN) * 32;
        const int dy = (KD == 9) ? d / 3 : 0;
        const int dx = (KD == 9) ? d % 3 : 0;
        const int iy0 = STRIDE * y0 + dy - PAD, ix0 = STRIDE * x0 + dx - PAD;
        const bool v0 = ((unsigned)iy0 < (unsigned)IH) && ((unsigned)ix0 < (unsigned)IH);
        const u16* P0 = v0 ? F + fb + ((size_t)iy0 * IH + ix0) * IC + lc : zp + lc;
        const int kd = d * IC;
        GLD16(P0 + ic0,      &As[bi][(wid * 16) * 32]);
        GLD16(q0 + kd + ic0, &Bs[bi][(wid * 16) * 32]);
        GLD16(q1 + kd + ic0, &Bs[bi][(64 + wid * 16) * 32]);
    };

    const f32x4 fzero = {0.f, 0.f, 0.f, 0.f};
    f32x4 acc[2][4];
    #pragma unroll
    for (int i = 0; i < 2; ++i)
        #pragma unroll
        for (int j = 0; j < 4; ++j) acc[i][j] = fzero;

    stage(0, 0);
    __syncthreads();                      // drain prologue stage (vmcnt 0)
    int buf = 0;
    #pragma unroll 2
    for (int s = 0; s < NT; ++s) {
        if (s + 1 < NT) stage(buf ^ 1, s + 1);   // prefetch next step

        bf16x8 af[2], bfr[4];
        #pragma unroll
        for (int i = 0; i < 2; ++i)
            af[i] = *(const bf16x8*)&As[buf][(wm + i * 16 + l16) * 32 + q8];
        #pragma unroll
        for (int j = 0; j < 4; ++j)
            bfr[j] = *(const bf16x8*)&Bs[buf][(wn + j * 16 + l16) * 32 + q8];
        #pragma unroll
        for (int i = 0; i < 2; ++i)
            #pragma unroll
            for (int j = 0; j < 4; ++j)
                acc[i][j] = __builtin_amdgcn_mfma_f32_16x16x32_bf16(af[i], bfr[j], acc[i][j], 0, 0, 0);

        __syncthreads();                  // next-step loads landed; bufs safe
        buf ^= 1;
    }

    const int q4 = (lane >> 4) * 4;
    if (EPI == 0) {
        #pragma unroll
        for (int i = 0; i < 2; ++i)
            #pragma unroll
            for (int j = 0; j < 4; ++j)
                #pragma unroll
                for (int r = 0; r < 4; ++r) {
                    const int ml = m0 + wm + i * 16 + q4 + r;
                    const int nl = n0 + wn + j * 16 + l16;
                    C[((size_t)b * 1024 + ml) * 256 + nl] = acc[i][j][r];
                }
        // fused GN partial stats: j-pair {0,1} -> group base, {2,3} -> base+1
        #pragma unroll
        for (int jp = 0; jp < 2; ++jp) {
            float s = 0.f, s2 = 0.f;
            #pragma unroll
            for (int j = 2 * jp; j < 2 * jp + 2; ++j)
                #pragma unroll
                for (int i = 0; i < 2; ++i)
                    #pragma unroll
                    for (int r = 0; r < 4; ++r) {
                        const float v = acc[i][j][r];
                        s += v; s2 += v * v;
                    }
            #pragma unroll
            for (int off = 32; off > 0; off >>= 1) {
                s  += __shfl_down(s,  off);
                s2 += __shfl_down(s2, off);
            }
            if (lane == 0) {
                const int g = ((n0 + wn) >> 5) + jp;
                atomicAdd(&stats[(b * NG_ + g) * 2 + 0], s);
                atomicAdd(&stats[(b * NG_ + g) * 2 + 1], s2);
            }
        }
    } else {
        #pragma unroll
        for (int j = 0; j < 4; ++j) {
            const int oc = n0 + wn + j * 16 + l16;
            const int gg = oc >> 5;
            const float ss  = stats[(b * NG_ + gg) * 2 + 0];
            const float ss2 = stats[(b * NG_ + gg) * 2 + 1];
            const float mean = ss * (1.0f / 32768.0f);
            const float rstd = rsqrtf(ss2 * (1.0f / 32768.0f) - mean * mean + EPS);
            const float ga = gamma[oc] * rstd;
            const float bb = beta[oc] - mean * ga;
            #pragma unroll
            for (int i = 0; i < 2; ++i) {
                const int nb = m0 + wm + i * 16 + q4;
                float4 o;
                #pragma unroll
                for (int r = 0; r < 4; ++r) {
                    float v = D2[((size_t)b * 1024 + nb + r) * 256 + oc] * ga + bb + acc[i][j][r];
                    ((float*)&o)[r] = fmaxf(v, 0.f);
                }
                *(float4*)&C[((size_t)b * OC + oc) * 1024 + nb] = o;
            }
        }
    }
}

// ---------------------------------------------------------------------------
extern "C" void kernel_launch(void* const* d_in, const int* in_sizes, int n_in,
                              void* d_out, int out_size, void* d_ws, size_t ws_size,
                              hipStream_t stream) {
    const float* x        = (const float*)d_in[0];
    const float* z        = (const float*)d_in[1];
    const float* base_w1  = (const float*)d_in[2];
    const float* head_w1  = (const float*)d_in[3];
    const float* head_b1  = (const float*)d_in[4];
    const float* gn_w1    = (const float*)d_in[5];
    const float* gn_b1    = (const float*)d_in[6];
    const float* base_w2  = (const float*)d_in[7];
    const float* head_w2  = (const float*)d_in[8];
    const float* head_b2  = (const float*)d_in[9];
    const float* gn_w2    = (const float*)d_in[10];
    const float* gn_b2    = (const float*)d_in[11];
    const float* base_wsc = (const float*)d_in[12];
    const float* head_wsc = (const float*)d_in[13];
    const float* head_bsc = (const float*)d_in[14];

    char* ws = (char*)d_ws;
    u16*   xT  = (u16*)(ws + OFF_XT);
    u16*   A1  = (u16*)(ws + OFF_A1);
    u16*   A2  = (u16*)(ws + OFF_A2);
    u16*   Asc = (u16*)(ws + OFF_ASC);
    float* o12 = (float*)(ws + OFF_O12);
    u16*   yT  = (u16*)(ws + OFF_YT);
    float* st1 = (float*)(ws + OFF_ST1);
    float* st2 = (float*)(ws + OFF_ST2);
    u16*   zp  = (u16*)(ws + OFF_ZP);
    float* out = (float*)d_out;

    hipMemsetAsync(zp, 0, 512, stream);
    hipMemsetAsync(st1, 0, 2048, stream);   // st1 + st2 (contiguous)

    // x -> NHWC bf16
    transpose_x_kern<<<dim3(16, 4, 16), 256, 0, stream>>>(x, xT);

    // hyper-weight generation: fused MFMA GEMM for all three heads
    gen_all_kern<<<7168, 256, 0, stream>>>(head_w1, head_b1, base_w1,
                                           head_w2, head_b2, base_w2,
                                           head_wsc, head_bsc, base_wsc,
                                           z, A1, A2, Asc);

    // conv1 (3x3 s2) implicit GEMM -> o12 [b][n][oc], fused GN1 stats
    conv_gemm<128, 64, 2, 9, 0><<<dim3(2, 16, 16), 256, 0, stream>>>(
        xT, A1, o12, zp, nullptr, st1, nullptr, nullptr);
    gn_apply_kern<<<2048, 256, 0, stream>>>(o12, st1, gn_w1, gn_b1, yT);

    // conv2 (3x3 s1) implicit GEMM -> o12 [b][n][oc], fused GN2 stats
    conv_gemm<256, 32, 1, 9, 0><<<dim3(2, 16, 16), 256, 0, stream>>>(
        yT, A2, o12, zp, nullptr, st2, nullptr, nullptr);

    // shortcut (1x1 s2) GEMM + fused GN2-apply + add + ReLU -> NCHW out
    conv_gemm<128, 64, 2, 1, 1><<<dim3(2, 16, 16), 256, 0, stream>>>(
        xT, Asc, out, zp, o12, st2, gn_w2, gn_b2);
}

// Round 9
// 427.349 us; speedup vs baseline: 1.0627x; 1.0627x over previous
//
#include <hip/hip_runtime.h>
#include <hip/hip_bf16.h>

typedef unsigned short u16;

#define B_   16
#define OC   256
#define ZD   64
#define NG_  8
#define EPS  1e-5f

typedef __attribute__((ext_vector_type(8))) __bf16 bf16x8;
typedef __attribute__((ext_vector_type(4))) float f32x4;
typedef __attribute__((ext_vector_type(8))) u16 ushort8;
typedef __attribute__((ext_vector_type(4))) u16 u16x4;

// Workspace layout (bytes), total ~71.3 MB (byte-identical to round-2 map)
#define OFF_XT  ((size_t)0)          // xT  bf16 [16][4096][128] = 16,777,216
#define OFF_A1  ((size_t)16777216)   // A1  bf16 [16][256][1152] =  9,437,184
#define OFF_A2  ((size_t)26214400)   // A2  bf16 [16][256][2304] = 18,874,368
#define OFF_ASC ((size_t)45088768)   // Asc bf16 [16][256][128]  =  1,048,576
#define OFF_O12 ((size_t)46137344)   // out1/out2 fp32 [16][1024][256] = 16,777,216
#define OFF_YT  ((size_t)62914560)   // yT  bf16 [16][1024][256] =  8,388,608
#define OFF_ST1 ((size_t)71303168)   // raw sums (s,s2) per (b,g): 1 KB
#define OFF_ST2 ((size_t)71304192)   // 1 KB
#define OFF_ZP  ((size_t)71305216)   // 512 B zero page

__device__ __forceinline__ u16 f2bf(float f) {
    union { float f; unsigned u; } x; x.f = f;
    unsigned r = x.u + 0x7fffu + ((x.u >> 16) & 1u);   // RNE
    return (u16)(r >> 16);
}

#define GLD16(gp, lp) __builtin_amdgcn_global_load_lds(                    \
        (const __attribute__((address_space(1))) void*)(gp),               \
        (__attribute__((address_space(3))) void*)(lp), 16, 0, 0)

// ---------------------------------------------------------------------------
// x NCHW fp32 -> xT [b][n=4096][ic=128] bf16.
// ---------------------------------------------------------------------------
__global__ void transpose_x_kern(const float* __restrict__ x, u16* __restrict__ xT) {
    const int b = blockIdx.z, ic0 = blockIdx.y * 32;
    const int n = blockIdx.x * 256 + threadIdx.x;
    const float* xp = x + ((size_t)b * 128 + ic0) * 4096 + n;
    u16* op = xT + ((size_t)b * 4096 + n) * 128 + ic0;
    float v[32];
    #pragma unroll
    for (int i = 0; i < 32; ++i) v[i] = xp[(size_t)i * 4096];
    #pragma unroll
    for (int c = 0; c < 4; ++c) {
        ushort8 o;
        #pragma unroll
        for (int j = 0; j < 8; ++j) o[j] = f2bf(v[c * 8 + j]);
        *(ushort8*)(op + c * 8) = o;
    }
}

// ---------------------------------------------------------------------------
// Weight gen as MFMA GEMM, output-coalesced, double-tile (round-6 verified,
// byte-identical).
// ---------------------------------------------------------------------------
template<int ICk, int KD>
__device__ __forceinline__ void gen_w_tile2(const float* __restrict__ hw,
                                            const float* __restrict__ hb,
                                            const float* __restrict__ bw,
                                            const float* __restrict__ z,
                                            u16* __restrict__ A, int t2) {
    const int lane = threadIdx.x & 63;
    const int l16 = lane & 15, q = lane >> 4;
    const int q8 = q * 8, q4 = q * 4;
    constexpr int ICT2 = ICk / 32;         // 32-ic double-tiles per (oc, d)
    constexpr int K = ICk * KD;

    const int oc  = t2 / (KD * ICT2);
    const int rem = t2 - oc * (KD * ICT2);
    const int d   = rem / ICT2;
    const int ic0 = (rem - d * ICT2) * 32;

    // hw rows for both sub-tiles: issue all 8 float4 loads up front
    const size_t nrow0 = (size_t)(oc * ICk + ic0 + l16) * KD + d;
    const float* hp0 = hw + nrow0 * ZD + q8;
    const float* hp1 = hp0 + (size_t)16 * KD * ZD;
    float4 a0 = *(const float4*)hp0,        a1 = *(const float4*)(hp0 + 4);
    float4 a2 = *(const float4*)(hp0 + 32), a3 = *(const float4*)(hp0 + 36);
    float4 c0 = *(const float4*)hp1,        c1 = *(const float4*)(hp1 + 4);
    float4 c2 = *(const float4*)(hp1 + 32), c3 = *(const float4*)(hp1 + 36);

    // z b-frags: z[batch=l16][k=q8+j] fp32 -> bf16 in-register
    const float* zpp = z + l16 * ZD + q8;
    float4 z0 = *(const float4*)zpp,        z1 = *(const float4*)(zpp + 4);
    float4 z2 = *(const float4*)(zpp + 32), z3 = *(const float4*)(zpp + 36);
    union { ushort8 u; bf16x8 h; } zb0, zb1;
    zb0.u[0]=f2bf(z0.x); zb0.u[1]=f2bf(z0.y); zb0.u[2]=f2bf(z0.z); zb0.u[3]=f2bf(z0.w);
    zb0.u[4]=f2bf(z1.x); zb0.u[5]=f2bf(z1.y); zb0.u[6]=f2bf(z1.z); zb0.u[7]=f2bf(z1.w);
    zb1.u[0]=f2bf(z2.x); zb1.u[1]=f2bf(z2.y); zb1.u[2]=f2bf(z2.z); zb1.u[3]=f2bf(z2.w);
    zb1.u[4]=f2bf(z3.x); zb1.u[5]=f2bf(z3.y); zb1.u[6]=f2bf(z3.z); zb1.u[7]=f2bf(z3.w);

    union { ushort8 u; bf16x8 h; } wa0, wa1, wc0, wc1;
    wa0.u[0]=f2bf(a0.x); wa0.u[1]=f2bf(a0.y); wa0.u[2]=f2bf(a0.z); wa0.u[3]=f2bf(a0.w);
    wa0.u[4]=f2bf(a1.x); wa0.u[5]=f2bf(a1.y); wa0.u[6]=f2bf(a1.z); wa0.u[7]=f2bf(a1.w);
    wa1.u[0]=f2bf(a2.x); wa1.u[1]=f2bf(a2.y); wa1.u[2]=f2bf(a2.z); wa1.u[3]=f2bf(a2.w);
    wa1.u[4]=f2bf(a3.x); wa1.u[5]=f2bf(a3.y); wa1.u[6]=f2bf(a3.z); wa1.u[7]=f2bf(a3.w);
    wc0.u[0]=f2bf(c0.x); wc0.u[1]=f2bf(c0.y); wc0.u[2]=f2bf(c0.z); wc0.u[3]=f2bf(c0.w);
    wc0.u[4]=f2bf(c1.x); wc0.u[5]=f2bf(c1.y); wc0.u[6]=f2bf(c1.z); wc0.u[7]=f2bf(c1.w);
    wc1.u[0]=f2bf(c2.x); wc1.u[1]=f2bf(c2.y); wc1.u[2]=f2bf(c2.z); wc1.u[3]=f2bf(c2.w);
    wc1.u[4]=f2bf(c3.x); wc1.u[5]=f2bf(c3.y); wc1.u[6]=f2bf(c3.z); wc1.u[7]=f2bf(c3.w);

    f32x4 accA = {0.f, 0.f, 0.f, 0.f}, accC = {0.f, 0.f, 0.f, 0.f};
    accA = __builtin_amdgcn_mfma_f32_16x16x32_bf16(wa0.h, zb0.h, accA, 0, 0, 0);
    accA = __builtin_amdgcn_mfma_f32_16x16x32_bf16(wa1.h, zb1.h, accA, 0, 0, 0);
    accC = __builtin_amdgcn_mfma_f32_16x16x32_bf16(wc0.h, zb0.h, accC, 0, 0, 0);
    accC = __builtin_amdgcn_mfma_f32_16x16x32_bf16(wc1.h, zb1.h, accC, 0, 0, 0);

    // base + bias for lane's 4 rows of each sub-tile (stride-KD gather)
    const size_t nb0 = (size_t)(oc * ICk + ic0 + q4) * KD + d;
    const size_t nb1 = nb0 + (size_t)16 * KD;
    float bsA[4], bsC[4];
    #pragma unroll
    for (int r = 0; r < 4; ++r) {
        bsA[r] = bw[nb0 + (size_t)r * KD] + hb[nb0 + (size_t)r * KD];
        bsC[r] = bw[nb1 + (size_t)r * KD] + hb[nb1 + (size_t)r * KD];
    }

    // D layout: col(l16)=batch, row(q*4+r)=ic offset -> 4 consecutive ic.
    u16* op = A + ((size_t)l16 * OC + oc) * (size_t)K + (size_t)d * ICk + ic0 + q4;
    u16x4 oA, oC;
    #pragma unroll
    for (int r = 0; r < 4; ++r) { oA[r] = f2bf(accA[r] + bsA[r]); oC[r] = f2bf(accC[r] + bsC[r]); }
    *(u16x4*)op = oA;
    *(u16x4*)(op + 16) = oC;
}

__global__ __launch_bounds__(256)
void gen_all_kern(const float* __restrict__ hw1, const float* __restrict__ hb1,
                  const float* __restrict__ bw1,
                  const float* __restrict__ hw2, const float* __restrict__ hb2,
                  const float* __restrict__ bw2,
                  const float* __restrict__ hwsc, const float* __restrict__ hbsc,
                  const float* __restrict__ bwsc,
                  const float* __restrict__ z,
                  u16* __restrict__ A1, u16* __restrict__ A2, u16* __restrict__ Asc) {
    const int wid = threadIdx.x >> 6;
    const int bx = blockIdx.x;
    if (bx < 4608) {
        gen_w_tile2<256, 9>(hw2, hb2, bw2, z, A2, bx * 4 + wid);            // 18432 t2
    } else if (bx < 6912) {
        gen_w_tile2<128, 9>(hw1, hb1, bw1, z, A1, (bx - 4608) * 4 + wid);   // 9216 t2
    } else {
        gen_w_tile2<128, 1>(hwsc, hbsc, bwsc, z, Asc, (bx - 6912) * 4 + wid); // 1024
    }
}

// ---------------------------------------------------------------------------
// GN1 apply + ReLU + bf16: out1 [b][n][256] fp32 -> yT bf16.
// stats holds RAW (s, s2) sums per (b,g); finalize inline.
// ---------------------------------------------------------------------------
__global__ void gn_apply_kern(const float* __restrict__ o1, const float* __restrict__ stats,
                              const float* __restrict__ gamma, const float* __restrict__ beta,
                              u16* __restrict__ yT) {
    const int gtid = blockIdx.x * 256 + threadIdx.x;
    const int c8 = gtid & 31;
    const int n  = (gtid >> 5) & 1023;
    const int b  = gtid >> 15;
    const int g  = c8 >> 2;
    const float s  = stats[(b * NG_ + g) * 2 + 0];
    const float s2 = stats[(b * NG_ + g) * 2 + 1];
    const float mean = s * (1.0f / 32768.0f);
    const float rstd = rsqrtf(s2 * (1.0f / 32768.0f) - mean * mean + EPS);
    const float* src = o1 + ((size_t)b * 1024 + n) * 256 + c8 * 8;
    float4 v0 = *(const float4*)src, v1 = *(const float4*)(src + 4);
    float4 g0 = *(const float4*)(gamma + c8 * 8), g1 = *(const float4*)(gamma + c8 * 8 + 4);
    float4 b0 = *(const float4*)(beta  + c8 * 8), b1 = *(const float4*)(beta  + c8 * 8 + 4);
    ushort8 o;
    o[0] = f2bf(fmaxf((v0.x - mean) * rstd * g0.x + b0.x, 0.f));
    o[1] = f2bf(fmaxf((v0.y - mean) * rstd * g0.y + b0.y, 0.f));
    o[2] = f2bf(fmaxf((v0.z - mean) * rstd * g0.z + b0.z, 0.f));
    o[3] = f2bf(fmaxf((v0.w - mean) * rstd * g0.w + b0.w, 0.f));
    o[4] = f2bf(fmaxf((v1.x - mean) * rstd * g1.x + b1.x, 0.f));
    o[5] = f2bf(fmaxf((v1.y - mean) * rstd * g1.y + b1.y, 0.f));
    o[6] = f2bf(fmaxf((v1.z - mean) * rstd * g1.z + b1.z, 0.f));
    o[7] = f2bf(fmaxf((v1.w - mean) * rstd * g1.w + b1.w, 0.f));
    *(ushort8*)(yT + ((size_t)b * 1024 + n) * 256 + c8 * 8) = o;
}

// ---------------------------------------------------------------------------
// Implicit-im2col MFMA conv GEMM, 64x128 tile, round-6 2-barrier structure
// with BK=64: two 32-ic k-slice planes staged per step (6 GLD16/wave),
// 16 MFMA per drain (was 8), K-steps halved. LDS layout per plane identical
// to round-6 (64B rows, measured 0 bank conflicts).
// EPI=0: plain stores + fused GN partial stats. EPI=1: GN2-apply+add+ReLU.
// ---------------------------------------------------------------------------
template<int IC, int IH, int STRIDE, int KD, int EPI>
__global__ __launch_bounds__(256, 2)
void conv_gemm(const u16* __restrict__ F, const u16* __restrict__ Wm,
               float* __restrict__ C, const u16* __restrict__ zp,
               const float* __restrict__ D2, float* __restrict__ stats,
               const float* __restrict__ gamma, const float* __restrict__ beta) {
    constexpr int K   = IC * KD;
    constexpr int PAD = (KD == 9) ? 1 : 0;
    __shared__ __align__(16) u16 As[2][64 * 32];
    __shared__ __align__(16) u16 Bs[2][128 * 32];

    const int b  = blockIdx.z;
    const int m0 = blockIdx.y * 64;      // spatial
    const int n0 = blockIdx.x * 128;     // oc
    const int tid = threadIdx.x, lane = tid & 63, wid = tid >> 6;
    const int wm = (wid >> 1) * 32, wn = (wid & 1) * 64;
    const int lr  = lane >> 2;
    const int lc  = (lane & 3) * 8;      // u16 offset within 64B row segment
    const int l16 = lane & 15, q8 = (lane >> 4) * 8;

    // spatial coords of this lane's A-staging row
    const int ra0 = m0 + wid * 16 + lr;
    const int y0 = ra0 >> 5, x0 = ra0 & 31;
    const size_t fb = (size_t)b * IH * IH * IC;

    const u16* q0 = Wm + ((size_t)b * OC + n0 + wid * 16 + lr) * K + lc;
    const u16* q1 = q0 + (size_t)64 * K;

    const f32x4 fzero = {0.f, 0.f, 0.f, 0.f};
    f32x4 acc[2][4];
    #pragma unroll
    for (int i = 0; i < 2; ++i)
        #pragma unroll
        for (int j = 0; j < 4; ++j) acc[i][j] = fzero;

    for (int d = 0; d < KD; ++d) {
        const int dy = (KD == 9) ? d / 3 : 0;
        const int dx = (KD == 9) ? d % 3 : 0;
        const int iy0 = STRIDE * y0 + dy - PAD, ix0 = STRIDE * x0 + dx - PAD;
        const bool v0 = ((unsigned)iy0 < (unsigned)IH) && ((unsigned)ix0 < (unsigned)IH);
        const u16* P0 = v0 ? F + fb + ((size_t)iy0 * IH + ix0) * IC + lc : zp + lc;
        const int kd = d * IC;
        for (int ic0 = 0; ic0 < IC; ic0 += 64) {
            __syncthreads();
            GLD16(P0 + ic0,           &As[0][(wid * 16) * 32]);
            GLD16(P0 + ic0 + 32,      &As[1][(wid * 16) * 32]);
            GLD16(q0 + kd + ic0,      &Bs[0][(wid * 16) * 32]);
            GLD16(q0 + kd + ic0 + 32, &Bs[1][(wid * 16) * 32]);
            GLD16(q1 + kd + ic0,      &Bs[0][(64 + wid * 16) * 32]);
            GLD16(q1 + kd + ic0 + 32, &Bs[1][(64 + wid * 16) * 32]);
            __syncthreads();

            #pragma unroll
            for (int k = 0; k < 2; ++k) {
                bf16x8 af[2], bfr[4];
                #pragma unroll
                for (int i = 0; i < 2; ++i)
                    af[i] = *(const bf16x8*)&As[k][(wm + i * 16 + l16) * 32 + q8];
                #pragma unroll
                for (int j = 0; j < 4; ++j)
                    bfr[j] = *(const bf16x8*)&Bs[k][(wn + j * 16 + l16) * 32 + q8];
                #pragma unroll
                for (int i = 0; i < 2; ++i)
                    #pragma unroll
                    for (int j = 0; j < 4; ++j)
                        acc[i][j] = __builtin_amdgcn_mfma_f32_16x16x32_bf16(af[i], bfr[j], acc[i][j], 0, 0, 0);
            }
        }
    }

    const int q4 = (lane >> 4) * 4;
    if (EPI == 0) {
        #pragma unroll
        for (int i = 0; i < 2; ++i)
            #pragma unroll
            for (int j = 0; j < 4; ++j)
                #pragma unroll
                for (int r = 0; r < 4; ++r) {
                    const int ml = m0 + wm + i * 16 + q4 + r;
                    const int nl = n0 + wn + j * 16 + l16;
                    C[((size_t)b * 1024 + ml) * 256 + nl] = acc[i][j][r];
                }
        // fused GN partial stats: j-pair {0,1} -> group base, {2,3} -> base+1
        #pragma unroll
        for (int jp = 0; jp < 2; ++jp) {
            float s = 0.f, s2 = 0.f;
            #pragma unroll
            for (int j = 2 * jp; j < 2 * jp + 2; ++j)
                #pragma unroll
                for (int i = 0; i < 2; ++i)
                    #pragma unroll
                    for (int r = 0; r < 4; ++r) {
                        const float v = acc[i][j][r];
                        s += v; s2 += v * v;
                    }
            #pragma unroll
            for (int off = 32; off > 0; off >>= 1) {
                s  += __shfl_down(s,  off);
                s2 += __shfl_down(s2, off);
            }
            if (lane == 0) {
                const int g = ((n0 + wn) >> 5) + jp;
                atomicAdd(&stats[(b * NG_ + g) * 2 + 0], s);
                atomicAdd(&stats[(b * NG_ + g) * 2 + 1], s2);
            }
        }
    } else {
        #pragma unroll
        for (int j = 0; j < 4; ++j) {
            const int oc = n0 + wn + j * 16 + l16;
            const int gg = oc >> 5;
            const float ss  = stats[(b * NG_ + gg) * 2 + 0];
            const float ss2 = stats[(b * NG_ + gg) * 2 + 1];
            const float mean = ss * (1.0f / 32768.0f);
            const float rstd = rsqrtf(ss2 * (1.0f / 32768.0f) - mean * mean + EPS);
            const float ga = gamma[oc] * rstd;
            const float bb = beta[oc] - mean * ga;
            #pragma unroll
            for (int i = 0; i < 2; ++i) {
                const int nb = m0 + wm + i * 16 + q4;
                float4 o;
                #pragma unroll
                for (int r = 0; r < 4; ++r) {
                    float v = D2[((size_t)b * 1024 + nb + r) * 256 + oc] * ga + bb + acc[i][j][r];
                    ((float*)&o)[r] = fmaxf(v, 0.f);
                }
                *(float4*)&C[((size_t)b * OC + oc) * 1024 + nb] = o;
            }
        }
    }
}

// ---------------------------------------------------------------------------
extern "C" void kernel_launch(void* const* d_in, const int* in_sizes, int n_in,
                              void* d_out, int out_size, void* d_ws, size_t ws_size,
                              hipStream_t stream) {
    const float* x        = (const float*)d_in[0];
    const float* z        = (const float*)d_in[1];
    const float* base_w1  = (const float*)d_in[2];
    const float* head_w1  = (const float*)d_in[3];
    const float* head_b1  = (const float*)d_in[4];
    const float* gn_w1    = (const float*)d_in[5];
    const float* gn_b1    = (const float*)d_in[6];
    const float* base_w2  = (const float*)d_in[7];
    const float* head_w2  = (const float*)d_in[8];
    const float* head_b2  = (const float*)d_in[9];
    const float* gn_w2    = (const float*)d_in[10];
    const float* gn_b2    = (const float*)d_in[11];
    const float* base_wsc = (const float*)d_in[12];
    const float* head_wsc = (const float*)d_in[13];
    const float* head_bsc = (const float*)d_in[14];

    char* ws = (char*)d_ws;
    u16*   xT  = (u16*)(ws + OFF_XT);
    u16*   A1  = (u16*)(ws + OFF_A1);
    u16*   A2  = (u16*)(ws + OFF_A2);
    u16*   Asc = (u16*)(ws + OFF_ASC);
    float* o12 = (float*)(ws + OFF_O12);
    u16*   yT  = (u16*)(ws + OFF_YT);
    float* st1 = (float*)(ws + OFF_ST1);
    float* st2 = (float*)(ws + OFF_ST2);
    u16*   zp  = (u16*)(ws + OFF_ZP);
    float* out = (float*)d_out;

    hipMemsetAsync(zp, 0, 512, stream);
    hipMemsetAsync(st1, 0, 2048, stream);   // st1 + st2 (contiguous)

    // x -> NHWC bf16
    transpose_x_kern<<<dim3(16, 4, 16), 256, 0, stream>>>(x, xT);

    // hyper-weight generation: fused MFMA GEMM for all three heads
    gen_all_kern<<<7168, 256, 0, stream>>>(head_w1, head_b1, base_w1,
                                           head_w2, head_b2, base_w2,
                                           head_wsc, head_bsc, base_wsc,
                                           z, A1, A2, Asc);

    // conv1 (3x3 s2) implicit GEMM -> o12 [b][n][oc], fused GN1 stats
    conv_gemm<128, 64, 2, 9, 0><<<dim3(2, 16, 16), 256, 0, stream>>>(
        xT, A1, o12, zp, nullptr, st1, nullptr, nullptr);
    gn_apply_kern<<<2048, 256, 0, stream>>>(o12, st1, gn_w1, gn_b1, yT);

    // conv2 (3x3 s1) implicit GEMM -> o12 [b][n][oc], fused GN2 stats
    conv_gemm<256, 32, 1, 9, 0><<<dim3(2, 16, 16), 256, 0, stream>>>(
        yT, A2, o12, zp, nullptr, st2, nullptr, nullptr);

    // shortcut (1x1 s2) GEMM + fused GN2-apply + add + ReLU -> NCHW out
    conv_gemm<128, 64, 2, 1, 1><<<dim3(2, 16, 16), 256, 0, stream>>>(
        xT, Asc, out, zp, o12, st2, gn_w2, gn_b2);
}